// Round 15
// baseline (224.795 us; speedup 1.0000x reference)
//
#include <hip/hip_runtime.h>
#include <hip/hip_bf16.h>
#include <stdint.h>
#include <stddef.h>

typedef __attribute__((ext_vector_type(8))) short short8;
typedef __attribute__((ext_vector_type(4))) float f32x4;
typedef __attribute__((ext_vector_type(4))) unsigned int u32x4;

#define DIM   512
#define NJ    17
#define NPART 5
#define NB    8192
#define KDIM  1536                  // 3 * 512
#define QROWS (NB*NPART)            // 40960
#define ROWB  (KDIM*2)              // 3072 bytes per Q/Wt row (bf16)

struct Cheb { float c[3][5][5]; };

__device__ __forceinline__ void gload_lds16(const void* g, void* l) {
  __builtin_amdgcn_global_load_lds((__attribute__((address_space(1))) void*)(g),
                                   (__attribute__((address_space(3))) void*)(l),
                                   16, 0, 0);
}

// ---------------- kernel A: pool + cheb -> Q bf16 (pre-swizzled) ----------------
__global__ __launch_bounds__(256) void pool_cheb_kernel(
    const float* __restrict__ x, __hip_bfloat16* __restrict__ Q, Cheb cb) {
  int gid = blockIdx.x * 256 + threadIdx.x;       // NB*128 threads
  int b  = gid >> 7;
  int c4 = gid & 127;                             // 4-elem d-chunk, d0 = c4*4
  const float* xb = x + (size_t)b * (NJ * DIM) + (c4 << 2);

  f32x4 pf[5];
#pragma unroll
  for (int p = 0; p < 5; ++p) pf[p] = (f32x4){0.f, 0.f, 0.f, 0.f};

  constexpr int jpart[NJ] = {2,0,0,0,1,1,1,2,2,2,2,3,3,3,4,4,4};
#pragma unroll
  for (int j = 0; j < NJ; ++j) {
    f32x4 a = __builtin_nontemporal_load(
        reinterpret_cast<const f32x4*>(xb + j * DIM));
    pf[jpart[j]] += a;
  }
  constexpr float scl[5] = {1.f/3.f, 1.f/3.f, 0.2f, 1.f/3.f, 1.f/3.f};
#pragma unroll
  for (int p = 0; p < 5; ++p) pf[p] *= scl[p];

  char* qb = reinterpret_cast<char*>(Q);
  int cj = c4 >> 1;                               // 16B chunk idx in k-segment
#pragma unroll
  for (int k = 0; k < 3; ++k) {
#pragma unroll
    for (int n = 0; n < 5; ++n) {
      int row = b * 5 + n;
      f32x4 s = cb.c[k][n][0] * pf[0] + cb.c[k][n][1] * pf[1] +
                cb.c[k][n][2] * pf[2] + cb.c[k][n][3] * pf[3] +
                cb.c[k][n][4] * pf[4];
      alignas(8) __hip_bfloat16 o[4];
#pragma unroll
      for (int i = 0; i < 4; ++i) o[i] = __float2bfloat16(s[i]);
      int swc = (cj & 7) ^ (row & 7);             // swizzled 16B chunk
      size_t off = (size_t)row * ROWB + (size_t)(k * 8 + (cj >> 3)) * 128 +
                   (size_t)swc * 16 + (size_t)(c4 & 1) * 8;
      *reinterpret_cast<ushort4*>(qb + off) = *reinterpret_cast<const ushort4*>(o);
    }
  }
}

// ---------------- kernel A2: weight [3,512,512] f32 -> Wt[e][k*512+d] bf16 ------
__global__ __launch_bounds__(256) void wt_kernel(
    const float* __restrict__ w, __hip_bfloat16* __restrict__ Wt) {
  int gid = blockIdx.x * 256 + threadIdx.x;       // 512 e * 192 chunks
  int e = gid & 511;
  int chunk = gid >> 9;                           // 0..191
  int kidx0 = chunk << 3;
  alignas(16) __hip_bfloat16 o[8];
#pragma unroll
  for (int i = 0; i < 8; ++i)
    o[i] = __float2bfloat16(w[(size_t)(kidx0 + i) * DIM + e]);
  int blk = kidx0 >> 6;
  int swc = ((kidx0 >> 3) & 7) ^ (e & 7);
  size_t off = (size_t)e * ROWB + (size_t)blk * 128 + (size_t)swc * 16;
  *reinterpret_cast<u32x4*>(reinterpret_cast<char*>(Wt) + off) =
      *reinterpret_cast<const u32x4*>(o);
}

// ---------------- kernel B: 160x128 tile, 2 blocks/CU, 2-phase dbuf -------------
// The untested occupancy cell: 2 CO-RESIDENT blocks per CU with the proven
// LDS-dbuf K-loop (72KB/block: A 2x20KB + B 2x16KB <= 80KB for 2/CU).
// 1024 blocks = 2 generations of 512: gen1's 139MB epilogue write burst
// overlaps gen2's K-loop on the same CU; only gen2's half-tail is exposed.
// (r13 failed at 1 blk/CU: generations are per-CU serial; r14 failed without
// LDS-B: L2 latency on the MFMA critical path.) 4 waves (2M x 2N), acc[5][4].
__global__ __launch_bounds__(256) void gemm_2res_kernel(
    const __hip_bfloat16* __restrict__ Q, const __hip_bfloat16* __restrict__ Wt,
    const float* __restrict__ bias, float* __restrict__ out) {
  extern __shared__ __align__(16) char LDSbuf[];
  char* As0 = LDSbuf;                 // 160 x 128B = 20 KB
  char* As1 = LDSbuf + 20480;
  char* Bs0 = LDSbuf + 40960;         // 128 x 128B = 16 KB
  char* Bs1 = LDSbuf + 57344;         // total 72 KB

  int tid  = threadIdx.x;
  int lane = tid & 63;
  int wave = tid >> 6;                // 0..3
  int wr = wave >> 1, wc = wave & 1;  // 2M x 2N wave grid, 80x64 out each
  int m0 = blockIdx.y * 160;
  int n0 = blockIdx.x * 128;

  f32x4 acc[5][4] = {};

  const char* qb = reinterpret_cast<const char*>(Q);
  const char* wb = reinterpret_cast<const char*>(Wt);
  int sr8 = lane >> 3;                // row within 8-row group (0..7)
  int sc  = (lane & 7) * 16;          // 16B chunk within 128B row-block

  // stage: A 20 row-groups (5/wave), B 16 row-groups (4/wave)
  auto stage = [&](char* Abuf, char* Bbuf, int ks) {
#pragma unroll
    for (int i = 0; i < 5; ++i) {
      int g = wave + i * 4;
      gload_lds16(qb + (size_t)(m0 + g * 8 + sr8) * ROWB + (size_t)ks * 128 + sc,
                  Abuf + g * 1024);
    }
#pragma unroll
    for (int i = 0; i < 4; ++i) {
      int g = wave + i * 4;
      gload_lds16(wb + (size_t)(n0 + g * 8 + sr8) * ROWB + (size_t)ks * 128 + sc,
                  Bbuf + g * 1024);
    }
  };

  auto compute = [&](const char* Abuf, const char* Bbuf) {
#pragma unroll
    for (int kk = 0; kk < 2; ++kk) {
      short8 af[5], bf[4];
#pragma unroll
      for (int mi = 0; mi < 5; ++mi) {
        int r = wr * 80 + mi * 16 + (lane & 15);
        int c7 = (kk * 4 + (lane >> 4)) ^ (r & 7);
        af[mi] = *reinterpret_cast<const short8*>(Abuf + r * 128 + c7 * 16);
      }
#pragma unroll
      for (int nj = 0; nj < 4; ++nj) {
        int r = wc * 64 + nj * 16 + (lane & 15);
        int c7 = (kk * 4 + (lane >> 4)) ^ (r & 7);
        bf[nj] = *reinterpret_cast<const short8*>(Bbuf + r * 128 + c7 * 16);
      }
#pragma unroll
      for (int mi = 0; mi < 5; ++mi)
#pragma unroll
        for (int nj = 0; nj < 4; ++nj)
          acc[mi][nj] = __builtin_amdgcn_mfma_f32_16x16x32_bf16(
              af[mi], bf[nj], acc[mi][nj], 0, 0, 0);
    }
  };

  // ---- pipelined K-loop: 24 steps, stage(next) before compute(cur) ----
  stage(As0, Bs0, 0);
  __syncthreads();
  for (int ks = 0; ks < 22; ks += 2) {
    stage(As1, Bs1, ks + 1);
    compute(As0, Bs0);
    __syncthreads();
    stage(As0, Bs0, ks + 2);
    compute(As1, Bs1);
    __syncthreads();
  }
  stage(As1, Bs1, 23);
  compute(As0, Bs0);        // step 22
  __syncthreads();
  compute(As1, Bs1);        // step 23
  __syncthreads();          // all compute done before epilogue reuses LDS

  // ---- epilogue: bias + LDS transpose-stage + plain float4 scatter ----
  float bs[4];
#pragma unroll
  for (int ni = 0; ni < 4; ++ni)
    bs[ni] = bias[n0 + wc * 64 + ni * 16 + (lane & 15)];

  char* eb = LDSbuf + wave * 4352;    // 16 rows x 68 f32 per wave (17.4 KB)
  int g4 = lane >> 4;                 // 0..3
  int cc = lane & 15;                 // 0..15

#pragma unroll
  for (int mi = 0; mi < 5; ++mi) {
    // write 16 rows x 64 cols f32 with bias (stride 68: <=2-way banks = free)
#pragma unroll
    for (int ni = 0; ni < 4; ++ni)
#pragma unroll
      for (int j = 0; j < 4; ++j)
        *reinterpret_cast<float*>(
            eb + (((g4 * 4 + j) * 68 + ni * 16 + cc) << 2)) =
            acc[mi][ni][j] + bs[ni];

    // read back coalesced: 4 x ds_read_b128, lane -> (row t*4+g4, col cc*4)
#pragma unroll
    for (int t = 0; t < 4; ++t) {
      u32x4 v4 = *reinterpret_cast<const u32x4*>(
          eb + ((((t * 4 + g4) * 68) + cc * 4) << 2));
      int R = m0 + wr * 80 + mi * 16 + t * 4 + g4;  // part row = b*5+n
      unsigned bb = (unsigned)R / 5u;
      int n = R - (int)bb * 5;
      unsigned mask = (n == 0) ? 0x0000Eu :
                      (n == 1) ? 0x00070u :
                      (n == 2) ? 0x00781u :
                      (n == 3) ? 0x03800u : 0x1C000u;
      float* op = out + (size_t)bb * (NJ * DIM) + (n0 + wc * 64 + cc * 4);
      while (mask) {
        int jn = __builtin_ctz(mask);
        mask &= mask - 1;
        *reinterpret_cast<u32x4*>(op + jn * DIM) = v4;   // plain store
      }
    }
  }
}

extern "C" void kernel_launch(void* const* d_in, const int* in_sizes, int n_in,
                              void* d_out, int out_size, void* d_ws, size_t ws_size,
                              hipStream_t stream) {
  const float* x    = (const float*)d_in[0];   // [8192,17,512]
  const float* w    = (const float*)d_in[1];   // [3,1,512,512]
  const float* bias = (const float*)d_in[2];   // [1,1,512]
  float* out = (float*)d_out;                  // [8192,17,512]

  __hip_bfloat16* Q  = (__hip_bfloat16*)d_ws;
  __hip_bfloat16* Wt = (__hip_bfloat16*)((char*)d_ws + (size_t)QROWS * ROWB);

  // host-side Cheb basis (K=2): T0=I, T1=L, T2=2L^2-I with L = I - rownorm(adj)
  Cheb cb;
  {
    double A[5][5] = {};
    const int e0[4] = {0, 1, 2, 2}, e1[4] = {2, 2, 3, 4};
    for (int t = 0; t < 4; ++t) { A[e0[t]][e1[t]] = 1.0; A[e1[t]][e0[t]] = 1.0; }
    for (int i = 0; i < 5; ++i) A[i][i] += 1.0;
    for (int i = 0; i < 5; ++i) {
      double rs = 0; for (int j = 0; j < 5; ++j) rs += A[i][j];
      for (int j = 0; j < 5; ++j) A[i][j] /= rs;
    }
    double L[5][5], T2[5][5];
    for (int i = 0; i < 5; ++i)
      for (int j = 0; j < 5; ++j) L[i][j] = (i == j ? 1.0 : 0.0) - A[i][j];
    for (int i = 0; i < 5; ++i)
      for (int j = 0; j < 5; ++j) {
        double s = 0; for (int m = 0; m < 5; ++m) s += L[i][m] * L[m][j];
        T2[i][j] = 2.0 * s - (i == j ? 1.0 : 0.0);
      }
    for (int i = 0; i < 5; ++i)
      for (int j = 0; j < 5; ++j) {
        cb.c[0][i][j] = (float)(i == j ? 1.0 : 0.0);
        cb.c[1][i][j] = (float)L[i][j];
        cb.c[2][i][j] = (float)T2[i][j];
      }
  }

  pool_cheb_kernel<<<(NB * 128) / 256, 256, 0, stream>>>(x, Q, cb);
  wt_kernel<<<(DIM * (KDIM / 8)) / 256, 256, 0, stream>>>(w, Wt);

  const int DYN_LDS = 73728;  // 72 KB -> 2 blocks/CU
  (void)hipFuncSetAttribute(
      reinterpret_cast<const void*>(gemm_2res_kernel),
      hipFuncAttributeMaxDynamicSharedMemorySize, DYN_LDS);
  gemm_2res_kernel<<<dim3(DIM / 128, QROWS / 160), 256, DYN_LDS, stream>>>(
      Q, Wt, bias, out);
}

// Round 16
// 170.248 us; speedup vs baseline: 1.3204x; 1.3204x over previous
//
#include <hip/hip_runtime.h>
#include <hip/hip_bf16.h>
#include <stdint.h>
#include <stddef.h>

typedef __attribute__((ext_vector_type(8))) short short8;
typedef __attribute__((ext_vector_type(4))) float f32x4;
typedef __attribute__((ext_vector_type(4))) unsigned int u32x4;

#define DIM   512
#define NJ    17
#define NPART 5
#define NB    8192
#define KDIM  1536                  // 3 * 512
#define QROWS (NB*NPART)            // 40960
#define ROWB  (KDIM*2)              // 3072 bytes per Q/Wt row (bf16)

struct Cheb { float c[3][5][5]; };

__device__ __forceinline__ void gload_lds16(const void* g, void* l) {
  __builtin_amdgcn_global_load_lds((__attribute__((address_space(1))) void*)(g),
                                   (__attribute__((address_space(3))) void*)(l),
                                   16, 0, 0);
}

// ---------------- kernel A: pool + cheb -> Q bf16 (pre-swizzled) ----------------
// One float4 (4 d-elems) per thread; NT loads of x (read-once; keep L3 for Q).
// Q layout: row r = b*5+n. Within each 128B K-block, 16B chunk index is XORed
// with (r&7) so a LINEAR global_load_lds yields the conflict-free LDS layout.
__global__ __launch_bounds__(256) void pool_cheb_kernel(
    const float* __restrict__ x, __hip_bfloat16* __restrict__ Q, Cheb cb) {
  int gid = blockIdx.x * 256 + threadIdx.x;       // NB*128 threads
  int b  = gid >> 7;
  int c4 = gid & 127;                             // 4-elem d-chunk, d0 = c4*4
  const float* xb = x + (size_t)b * (NJ * DIM) + (c4 << 2);

  f32x4 pf[5];
#pragma unroll
  for (int p = 0; p < 5; ++p) pf[p] = (f32x4){0.f, 0.f, 0.f, 0.f};

  constexpr int jpart[NJ] = {2,0,0,0,1,1,1,2,2,2,2,3,3,3,4,4,4};
#pragma unroll
  for (int j = 0; j < NJ; ++j) {
    f32x4 a = __builtin_nontemporal_load(
        reinterpret_cast<const f32x4*>(xb + j * DIM));
    pf[jpart[j]] += a;
  }
  constexpr float scl[5] = {1.f/3.f, 1.f/3.f, 0.2f, 1.f/3.f, 1.f/3.f};
#pragma unroll
  for (int p = 0; p < 5; ++p) pf[p] *= scl[p];

  char* qb = reinterpret_cast<char*>(Q);
  int cj = c4 >> 1;                               // 16B chunk idx in k-segment
#pragma unroll
  for (int k = 0; k < 3; ++k) {
#pragma unroll
    for (int n = 0; n < 5; ++n) {
      int row = b * 5 + n;
      f32x4 s = cb.c[k][n][0] * pf[0] + cb.c[k][n][1] * pf[1] +
                cb.c[k][n][2] * pf[2] + cb.c[k][n][3] * pf[3] +
                cb.c[k][n][4] * pf[4];
      alignas(8) __hip_bfloat16 o[4];
#pragma unroll
      for (int i = 0; i < 4; ++i) o[i] = __float2bfloat16(s[i]);
      int swc = (cj & 7) ^ (row & 7);             // swizzled 16B chunk
      size_t off = (size_t)row * ROWB + (size_t)(k * 8 + (cj >> 3)) * 128 +
                   (size_t)swc * 16 + (size_t)(c4 & 1) * 8;
      *reinterpret_cast<ushort4*>(qb + off) = *reinterpret_cast<const ushort4*>(o);
    }
  }
}

// ---------------- kernel A2: weight [3,512,512] f32 -> Wt[e][k*512+d] bf16 ------
__global__ __launch_bounds__(256) void wt_kernel(
    const float* __restrict__ w, __hip_bfloat16* __restrict__ Wt) {
  int gid = blockIdx.x * 256 + threadIdx.x;       // 512 e * 192 chunks
  int e = gid & 511;
  int chunk = gid >> 9;                           // 0..191
  int kidx0 = chunk << 3;
  alignas(16) __hip_bfloat16 o[8];
#pragma unroll
  for (int i = 0; i < 8; ++i)
    o[i] = __float2bfloat16(w[(size_t)(kidx0 + i) * DIM + e]);
  int blk = kidx0 >> 6;
  int swc = ((kidx0 >> 3) & 7) ^ (e & 7);
  size_t off = (size_t)e * ROWB + (size_t)blk * 128 + (size_t)swc * 16;
  *reinterpret_cast<u32x4*>(reinterpret_cast<char*>(Wt) + off) =
      *reinterpret_cast<const u32x4*>(o);
}

// ---------------- kernel B: 320x256 tile, 1 block/CU, 2-phase dbuf --------------
// Champion structure (171.0us). 256 blocks = one generation; 8 waves (4M x 2N),
// each wave 80x128 (acc[5][8]); LDS 144KB dynamic, double-buffered; plain
// stores in epilogue (NT was neutral here, amplifies writes in narrow patterns).
__global__ __launch_bounds__(512, 2) void gemm_big_kernel(
    const __hip_bfloat16* __restrict__ Q, const __hip_bfloat16* __restrict__ Wt,
    const float* __restrict__ bias, float* __restrict__ out) {
  extern __shared__ __align__(16) char LDSbuf[];
  char* As0 = LDSbuf;                 // 320 x 128B = 40 KB
  char* As1 = LDSbuf + 40960;
  char* Bs0 = LDSbuf + 81920;         // 256 x 128B = 32 KB
  char* Bs1 = LDSbuf + 114688;        // total 144 KB

  int tid  = threadIdx.x;
  int lane = tid & 63;
  int wave = tid >> 6;                // 0..7
  int wr = wave >> 1, wc = wave & 1;  // 4M x 2N wave grid
  int m0 = blockIdx.y * 320;
  int n0 = blockIdx.x * 256;

  f32x4 acc[5][8] = {};

  const char* qb = reinterpret_cast<const char*>(Q);
  const char* wb = reinterpret_cast<const char*>(Wt);
  int sr8 = lane >> 3;                // row within 8-row group (0..7)
  int sc  = (lane & 7) * 16;          // 16B chunk within 128B row-block

  const char* abase = qb + (size_t)(m0 + wave * 40 + sr8) * ROWB + sc;
  const char* bbase = wb + (size_t)(n0 + wave * 32 + sr8) * ROWB + sc;
  size_t aoff = wave * 5120;
  size_t boff = wave * 4096;

  auto stage = [&](char* Abuf, char* Bbuf, int ks) {
#pragma unroll
    for (int i = 0; i < 5; ++i)
      gload_lds16(abase + (size_t)i * (8 * ROWB) + (size_t)ks * 128,
                  Abuf + aoff + i * 1024);
#pragma unroll
    for (int i = 0; i < 4; ++i)
      gload_lds16(bbase + (size_t)i * (8 * ROWB) + (size_t)ks * 128,
                  Bbuf + boff + i * 1024);
  };

  auto compute = [&](const char* Abuf, const char* Bbuf) {
#pragma unroll
    for (int kk = 0; kk < 2; ++kk) {
      short8 af[5];
#pragma unroll
      for (int mi = 0; mi < 5; ++mi) {
        int r = wr * 80 + mi * 16 + (lane & 15);
        int c7 = (kk * 4 + (lane >> 4)) ^ (r & 7);
        af[mi] = *reinterpret_cast<const short8*>(Abuf + r * 128 + c7 * 16);
      }
#pragma unroll
      for (int h = 0; h < 2; ++h) {
        short8 bf[4];
#pragma unroll
        for (int nj = 0; nj < 4; ++nj) {
          int r = wc * 128 + (h * 4 + nj) * 16 + (lane & 15);
          int c7 = (kk * 4 + (lane >> 4)) ^ (r & 7);
          bf[nj] = *reinterpret_cast<const short8*>(Bbuf + r * 128 + c7 * 16);
        }
#pragma unroll
        for (int mi = 0; mi < 5; ++mi)
#pragma unroll
          for (int nj = 0; nj < 4; ++nj)
            acc[mi][h * 4 + nj] = __builtin_amdgcn_mfma_f32_16x16x32_bf16(
                af[mi], bf[nj], acc[mi][h * 4 + nj], 0, 0, 0);
      }
    }
  };

  // ---- pipelined K-loop: 24 steps, stage(next) before compute(cur) ----
  stage(As0, Bs0, 0);
  __syncthreads();
  for (int ks = 0; ks < 22; ks += 2) {
    stage(As1, Bs1, ks + 1);
    compute(As0, Bs0);
    __syncthreads();
    stage(As0, Bs0, ks + 2);
    compute(As1, Bs1);
    __syncthreads();
  }
  stage(As1, Bs1, 23);
  compute(As0, Bs0);        // step 22
  __syncthreads();
  compute(As1, Bs1);        // step 23
  __syncthreads();          // all compute done before epilogue reuses LDS

  // ---- epilogue: bias + LDS transpose-stage + plain float4 scatter ----
  float bs[8];
#pragma unroll
  for (int ni = 0; ni < 8; ++ni)
    bs[ni] = bias[n0 + wc * 128 + ni * 16 + (lane & 15)];

  char* eb = LDSbuf + wave * 8448;    // 16 rows x 132 f32 = 8448B per wave
  int halfsel = lane >> 5;            // 0/1
  int col4 = lane & 31;               // float4 col index (0..31)

#pragma unroll
  for (int mi = 0; mi < 5; ++mi) {
#pragma unroll
    for (int ni = 0; ni < 8; ++ni)
#pragma unroll
      for (int j = 0; j < 4; ++j) {
        int row = (lane >> 4) * 4 + j;
        *reinterpret_cast<float*>(
            eb + ((row * 132 + ni * 16 + (lane & 15)) << 2)) =
            acc[mi][ni][j] + bs[ni];
      }
#pragma unroll
    for (int rr = 0; rr < 8; ++rr) {
      int row = rr * 2 + halfsel;
      u32x4 v4 = *reinterpret_cast<const u32x4*>(
          eb + ((row * 132 + col4 * 4) << 2));
      int R = m0 + wr * 80 + mi * 16 + row;       // part row = b*5+n
      unsigned bb = (unsigned)R / 5u;
      int n = R - (int)bb * 5;
      unsigned mask = (n == 0) ? 0x0000Eu :
                      (n == 1) ? 0x00070u :
                      (n == 2) ? 0x00781u :
                      (n == 3) ? 0x03800u : 0x1C000u;
      float* op = out + (size_t)bb * (NJ * DIM) + (n0 + wc * 128 + col4 * 4);
      while (mask) {
        int jn = __builtin_ctz(mask);
        mask &= mask - 1;
        *reinterpret_cast<u32x4*>(op + jn * DIM) = v4;   // plain store
      }
    }
  }
}

extern "C" void kernel_launch(void* const* d_in, const int* in_sizes, int n_in,
                              void* d_out, int out_size, void* d_ws, size_t ws_size,
                              hipStream_t stream) {
  const float* x    = (const float*)d_in[0];   // [8192,17,512]
  const float* w    = (const float*)d_in[1];   // [3,1,512,512]
  const float* bias = (const float*)d_in[2];   // [1,1,512]
  float* out = (float*)d_out;                  // [8192,17,512]

  __hip_bfloat16* Q  = (__hip_bfloat16*)d_ws;
  __hip_bfloat16* Wt = (__hip_bfloat16*)((char*)d_ws + (size_t)QROWS * ROWB);

  // host-side Cheb basis (K=2): T0=I, T1=L, T2=2L^2-I with L = I - rownorm(adj)
  Cheb cb;
  {
    double A[5][5] = {};
    const int e0[4] = {0, 1, 2, 2}, e1[4] = {2, 2, 3, 4};
    for (int t = 0; t < 4; ++t) { A[e0[t]][e1[t]] = 1.0; A[e1[t]][e0[t]] = 1.0; }
    for (int i = 0; i < 5; ++i) A[i][i] += 1.0;
    for (int i = 0; i < 5; ++i) {
      double rs = 0; for (int j = 0; j < 5; ++j) rs += A[i][j];
      for (int j = 0; j < 5; ++j) A[i][j] /= rs;
    }
    double L[5][5], T2[5][5];
    for (int i = 0; i < 5; ++i)
      for (int j = 0; j < 5; ++j) L[i][j] = (i == j ? 1.0 : 0.0) - A[i][j];
    for (int i = 0; i < 5; ++i)
      for (int j = 0; j < 5; ++j) {
        double s = 0; for (int m = 0; m < 5; ++m) s += L[i][m] * L[m][j];
        T2[i][j] = 2.0 * s - (i == j ? 1.0 : 0.0);
      }
    for (int i = 0; i < 5; ++i)
      for (int j = 0; j < 5; ++j) {
        cb.c[0][i][j] = (float)(i == j ? 1.0 : 0.0);
        cb.c[1][i][j] = (float)L[i][j];
        cb.c[2][i][j] = (float)T2[i][j];
      }
  }

  pool_cheb_kernel<<<(NB * 128) / 256, 256, 0, stream>>>(x, Q, cb);
  wt_kernel<<<(DIM * (KDIM / 8)) / 256, 256, 0, stream>>>(w, Wt);

  const int DYN_LDS = 147456;  // 144 KB
  (void)hipFuncSetAttribute(
      reinterpret_cast<const void*>(gemm_big_kernel),
      hipFuncAttributeMaxDynamicSharedMemorySize, DYN_LDS);
  gemm_big_kernel<<<dim3(DIM / 256, QROWS / 320), 512, DYN_LDS, stream>>>(
      Q, Wt, bias, out);
}